// Round 13
// baseline (435.667 us; speedup 1.0000x reference)
//
#include <hip/hip_runtime.h>
#include <hip/hip_bf16.h>
#include <hip/hip_fp16.h>
#include <math.h>

#define T_STEPS 512
#define NB      16
#define D_IN    512
#define CG      4096
#define CO      5120
#define LMAX    252
#define NEGF    (-1e30f)
#define SCORES_SZ 41943040LL   // NB * T_STEPS * CO
#define L2E 1.4426950408889634f
#define LN2 0.6931471805599453f
#define STAYT 0.36787944117144233f   // exp(2 - 3) tilted stay factor

typedef __attribute__((ext_vector_type(8))) short bf16x8;
typedef __attribute__((ext_vector_type(4))) float f32x4;

__device__ __forceinline__ float tanh5(float x) {
    x = fminf(fmaxf(x, -15.f), 15.f);
    float e = __expf(2.f * x);
    return 5.f * (e - 1.f) / (e + 1.f);
}
__device__ __forceinline__ unsigned short f2bf(float v) {
    __hip_bfloat16 h = __float2bfloat16(v);
    return *reinterpret_cast<unsigned short*>(&h);
}
__device__ __forceinline__ float h2f(unsigned short s) {
    union { unsigned short u; _Float16 h; } c; c.u = s;
    return (float)c.h;
}
__device__ __forceinline__ unsigned short f2h(float v) {
    union { unsigned short u; _Float16 h; } c; c.h = (_Float16)v;
    return c.u;
}
__device__ __forceinline__ void cvt8(uint4 u, float* g) {
    g[0] = h2f((unsigned short)(u.x & 0xffff)); g[1] = h2f((unsigned short)(u.x >> 16));
    g[2] = h2f((unsigned short)(u.y & 0xffff)); g[3] = h2f((unsigned short)(u.y >> 16));
    g[4] = h2f((unsigned short)(u.z & 0xffff)); g[5] = h2f((unsigned short)(u.z >> 16));
    g[6] = h2f((unsigned short)(u.w & 0xffff)); g[7] = h2f((unsigned short)(u.w >> 16));
}
// Clobber-free LDS-only step barrier (m201 pattern, rule #18).
__device__ __forceinline__ void xbar() {
    __builtin_amdgcn_sched_barrier(0);
    asm volatile("s_waitcnt lgkmcnt(0)");
    __builtin_amdgcn_s_barrier();
    __builtin_amdgcn_sched_barrier(0);
}
__device__ __forceinline__ void gll16(const unsigned short* g, unsigned short* l) {
    __builtin_amdgcn_global_load_lds((const __attribute__((address_space(1))) void*)g,
                                     (__attribute__((address_space(3))) void*)l, 16, 0, 0);
}
// Producer->consumer tile gate (cross-XCD safe: agent-scope atomics + fences).
__device__ __forceinline__ void wait_tile(unsigned int* done, int idx) {
    if (threadIdx.x == 0) {
        while (__hip_atomic_load(&done[idx], __ATOMIC_RELAXED, __HIP_MEMORY_SCOPE_AGENT) < 32u)
            __builtin_amdgcn_s_sleep(8);
    }
    __syncthreads();
    __builtin_amdgcn_fence(__ATOMIC_ACQUIRE, "agent");
}

// ---------------- fp32 -> bf16 conversion (RNE) ----------------
__global__ __launch_bounds__(256) void cvt_bf16_kernel(const float* __restrict__ src,
                                                       unsigned short* __restrict__ dst,
                                                       int n4) {
    int i = blockIdx.x * 256 + threadIdx.x;
    if (i < n4) {
        float4 v = *(reinterpret_cast<const float4*>(src) + i);
        ushort4 o;
        o.x = f2bf(v.x); o.y = f2bf(v.y); o.z = f2bf(v.z); o.w = f2bf(v.w);
        *(reinterpret_cast<ushort4*>(dst) + i) = o;
    }
}

// ---------------- MEGA kernel: fb consumer blocks (0..63) + GEMM producer blocks (64..2111) ----------------
// GEMM blocks remapped so row-tiles complete in fb consumption order: tb priority {0,3,1,2}
// (fwd roles eat t ascending: tiles 0,1; bwd roles eat t descending: tiles 3,2). Each GEMM
// block bumps done[n*4+tb] (agent scope) after its stores; fb gates on done[...]==32 only at
// tile transitions (2 waits per role). fb bodies are R10's fb2 verbatim (passed, absmax .031).
__global__ __launch_bounds__(256) void mega_kernel(
    const unsigned short* __restrict__ A16,
    const unsigned short* __restrict__ W16,
    const float* __restrict__ bias,
    float* __restrict__ out,
    unsigned short* __restrict__ e16,
    const int* __restrict__ ys_pad,
    const int* __restrict__ ys_lens,
    unsigned int* __restrict__ done,
    float* __restrict__ FA, float* __restrict__ FAe,
    float* __restrict__ FB, float* __restrict__ FBe,
    float* __restrict__ CAL, float* __restrict__ CBE)
{
    __shared__ unsigned char SH[32896];
    const int tid = threadIdx.x;

    if (blockIdx.x >= 64) {
        // ================= GEMM producer =================
        unsigned short* As = (unsigned short*)SH;            // 16KB
        unsigned short* Bs = (unsigned short*)(SH + 16384);  // 16KB
        const int g = blockIdx.x - 64;
        const int prio = g >> 9;                 // 0..3 (512 blocks per priority group)
        const int nb   = (g >> 5) & 15;
        const int x    = g & 31;
        const int tb   = (int)((0u | (3u << 2) | (1u << 4) | (2u << 6)) >> (2 * prio)) & 3; // {0,3,1,2}
        const int m0   = nb * 512 + tb * 128;
        const int n0   = x * 128;
        const int lane = tid & 63;
        const int wv   = __builtin_amdgcn_readfirstlane(tid >> 6);
        const int wr   = wv >> 1, wc = wv & 1;
        const int wbase = tid & 192;

        f32x4 acc[4][4];
        #pragma unroll
        for (int i = 0; i < 4; ++i)
            #pragma unroll
            for (int j = 0; j < 4; ++j) acc[i][j] = (f32x4){0.f, 0.f, 0.f, 0.f};

        const int l15 = lane & 15, lj = lane >> 4, l7 = lane & 7;

        for (int k0 = 0; k0 < D_IN; k0 += 64) {
            __syncthreads();
            #pragma unroll
            for (int i = 0; i < 4; ++i) {
                const int c   = i * 256 + tid;
                const int row = c >> 3;
                const int jg  = (c & 7) ^ (row & 7);
                const unsigned short* ga = A16 + (size_t)(m0 + row) * D_IN + k0 + jg * 8;
                const unsigned short* gb = W16 + (size_t)(n0 + row) * D_IN + k0 + jg * 8;
                gll16(ga, As + (size_t)(i * 256 + wbase) * 8);
                gll16(gb, Bs + (size_t)(i * 256 + wbase) * 8);
            }
            __syncthreads();
            #pragma unroll
            for (int ks = 0; ks < 2; ++ks) {
                bf16x8 af[4], bb[4];
                #pragma unroll
                for (int mi = 0; mi < 4; ++mi) {
                    const int row = wr * 64 + mi * 16 + l15;
                    const int jsw = (ks * 4 + lj) ^ l7;
                    af[mi] = *reinterpret_cast<const bf16x8*>(&As[row * 64 + jsw * 8]);
                }
                #pragma unroll
                for (int ni = 0; ni < 4; ++ni) {
                    const int row = wc * 64 + ni * 16 + l15;
                    const int jsw = (ks * 4 + lj) ^ l7;
                    bb[ni] = *reinterpret_cast<const bf16x8*>(&Bs[row * 64 + jsw * 8]);
                }
                #pragma unroll
                for (int mi = 0; mi < 4; ++mi)
                    #pragma unroll
                    for (int ni = 0; ni < 4; ++ni)
                        acc[mi][ni] = __builtin_amdgcn_mfma_f32_16x16x32_bf16(
                            af[mi], bb[ni], acc[mi][ni], 0, 0, 0);
            }
        }

        float bv[4];
        #pragma unroll
        for (int ni = 0; ni < 4; ++ni) bv[ni] = bias[n0 + wc * 64 + ni * 16 + l15];

        #pragma unroll
        for (int mi = 0; mi < 4; ++mi) {
            #pragma unroll
            for (int r = 0; r < 4; ++r) {
                const int m = m0 + wr * 64 + mi * 16 + lj * 4 + r;
                float* r1 = out + 16 + (size_t)m * CO;
                #pragma unroll
                for (int ni = 0; ni < 4; ++ni) {
                    const int n = n0 + wc * 64 + ni * 16 + l15;
                    const float v = tanh5(acc[mi][ni][r] + bv[ni]);
                    const int ch = (n >> 2) * 5 + (n & 3) + 1;
                    r1[ch] = v;
                    r1[ch + SCORES_SZ] = v;
                    if ((l15 & 3) == 0) {
                        r1[ch - 1] = 2.0f;
                        r1[ch - 1 + SCORES_SZ] = 2.0f;
                    }
                    e16[(size_t)m * CG + n] = f2h(__expf(v - 3.0f));
                }
            }
        }
        __syncthreads();   // drains vmcnt -> all block stores complete
        if (tid == 0) {
            __builtin_amdgcn_fence(__ATOMIC_RELEASE, "agent");
            __hip_atomic_fetch_add(&done[nb * 4 + tb], 1u,
                                   __ATOMIC_RELAXED, __HIP_MEMORY_SCOPE_AGENT);
        }
        return;
    }

    // ================= fb consumer (R10 fb2 bodies + tile gates) =================
    float (*buf)[1024] = (float(*)[1024])SH;         // 2 x 4KB
    float* wmax4 = (float*)(SH + 8192);
    int*   tcl   = (int*)(SH + 8208);
    const int role = blockIdx.x >> 4;
    const int n = blockIdx.x & 15;
    const int q = tid;
    const int w = q >> 6, lane = q & 63;
    const bool FWD = !(role & 1);

    if (role < 2) {
        // ---------------- CRF halves (prob domain) ----------------
        const unsigned short* eb = e16 + (size_t)(n * T_STEPS) * CG + 16 * q;
        float P0 = 1.f, P1 = 1.f, P2 = 1.f, P3 = 1.f, acc = 0.f;
        *(float4*)&buf[0][4 * q] = make_float4(1.f, 1.f, 1.f, 1.f);
        int have = FWD ? 0 : 3;
        wait_tile(done, n * 4 + have);
        uint4 pf[8][2];
        #pragma unroll
        for (int u = 0; u < 8; ++u) {
            const int row = FWD ? u : (511 - u);
            pf[u][0] = *(const uint4*)(eb + (size_t)row * CG);
            pf[u][1] = *(const uint4*)(eb + (size_t)row * CG + 8);
        }
        xbar();
        int cur = 0;
        for (int t = 0; t < 256; t += 8) {
            {
                const int la = (t + 11 < 255) ? (t + 11) : 255;
                const int tbo = FWD ? (la >> 7) : ((511 - la) >> 7);
                if (tbo != have) { wait_tile(done, n * 4 + tbo); have = tbo; }
            }
            #pragma unroll
            for (int u = 0; u < 8; ++u) {
                float g[16];
                cvt8(pf[u][0], g);
                cvt8(pf[u][1], g + 8);
                int tn = t + u + 8; if (tn > 255) tn = 255;
                const int row = FWD ? tn : (511 - tn);
                pf[u][0] = *(const uint4*)(eb + (size_t)row * CG);
                pf[u][1] = *(const uint4*)(eb + (size_t)row * CG + 8);
                float n0, n1, n2, n3;
                if (FWD) {
                    const float b0 = buf[cur][q];
                    const float b1 = buf[cur][q + 256];
                    const float b2 = buf[cur][q + 512];
                    const float b3 = buf[cur][q + 768];
                    n0 = fmaf(STAYT, P0, fmaf(g[0],  b0, g[1]  * b1) + fmaf(g[2],  b2, g[3]  * b3));
                    n1 = fmaf(STAYT, P1, fmaf(g[4],  b0, g[5]  * b1) + fmaf(g[6],  b2, g[7]  * b3));
                    n2 = fmaf(STAYT, P2, fmaf(g[8],  b0, g[9]  * b1) + fmaf(g[10], b2, g[11] * b3));
                    n3 = fmaf(STAYT, P3, fmaf(g[12], b0, g[13] * b1) + fmaf(g[14], b2, g[15] * b3));
                } else {
                    const float4 b4 = *(const float4*)&buf[cur][4 * q];
                    n0 = fmaf(STAYT, P0, fmaf(g[0], b4.x, g[4] * b4.y) + fmaf(g[8],  b4.z, g[12] * b4.w));
                    n1 = fmaf(STAYT, P1, fmaf(g[1], b4.x, g[5] * b4.y) + fmaf(g[9],  b4.z, g[13] * b4.w));
                    n2 = fmaf(STAYT, P2, fmaf(g[2], b4.x, g[6] * b4.y) + fmaf(g[10], b4.z, g[14] * b4.w));
                    n3 = fmaf(STAYT, P3, fmaf(g[3], b4.x, g[7] * b4.y) + fmaf(g[11], b4.z, g[15] * b4.w));
                }
                if (((t + u) & 7) == 1) {
                    const float wm = fmaxf(fmaxf(wmax4[0], wmax4[1]), fmaxf(wmax4[2], wmax4[3]));
                    const int e = (int)((__float_as_uint(wm) >> 23) & 0xff) - 127;
                    const float c = __uint_as_float((unsigned)(127 - e) << 23);
                    n0 *= c; n1 *= c; n2 *= c; n3 *= c;
                    acc += (float)e;
                }
                P0 = n0; P1 = n1; P2 = n2; P3 = n3;
                if (FWD) {
                    *(float4*)&buf[cur ^ 1][4 * q] = make_float4(P0, P1, P2, P3);
                } else {
                    buf[cur ^ 1][q]       = P0;
                    buf[cur ^ 1][q + 256] = P1;
                    buf[cur ^ 1][q + 512] = P2;
                    buf[cur ^ 1][q + 768] = P3;
                }
                if (((t + u) & 7) == 0) {
                    float m = fmaxf(fmaxf(P0, P1), fmaxf(P2, P3));
                    #pragma unroll
                    for (int msk = 1; msk < 64; msk <<= 1)
                        m = fmaxf(m, __shfl_xor(m, msk, 64));
                    if (lane == 0) wmax4[w] = m;
                }
                xbar();
                cur ^= 1;
            }
        }
        if (FWD) {
            *(float4*)&FA[n * 1024 + 4 * q] = make_float4(P0, P1, P2, P3);
            if (q == 0) FAe[n] = acc;
        } else {
            FB[n * 1024 + q]       = P0;
            FB[n * 1024 + q + 256] = P1;
            FB[n * 1024 + q + 512] = P2;
            FB[n * 1024 + q + 768] = P3;
            if (q == 0) FBe[n] = acc;
        }
    } else {
        // ---------------- CTC halves (log2 domain, per-lane depth-16 reg pipeline) ----------------
        float* abuf = &buf[0][0];
        tcl[q] = max(ys_pad[n * 256 + q] - 1, 0);
        xbar();
        int mch = 0; bool val;
        if (FWD) {
            val = (q >= 1 && q < LMAX);
            if (val) {
                const int code = tcl[q] * 256 + tcl[q + 1] * 64 + tcl[q + 2] * 16
                               + tcl[q + 3] * 4 + tcl[q + 4];
                mch = code * 4 + tcl[q - 1];
            }
        } else {
            val = (q < LMAX - 1);
            if (val) {
                const int code = tcl[q + 1] * 256 + tcl[q + 2] * 64 + tcl[q + 3] * 16
                               + tcl[q + 4] * 4 + tcl[q + 5];
                mch = code * 4 + tcl[q];
            }
        }
        const int li = ys_lens[n] - 5;
        float a = FWD ? ((q == 0) ? 0.f : NEGF)
                      : ((q == li) ? 0.f : NEGF);
        abuf[q] = a;
        int have = FWD ? 0 : 3;
        wait_tile(done, n * 4 + have);
        const unsigned short* eb = e16 + (size_t)(n * T_STEPS) * CG + mch;
        unsigned short pv[16];
        #pragma unroll
        for (int s = 0; s < 16; ++s) {
            const int row = FWD ? s : (511 - s);
            pv[s] = eb[(size_t)row * CG];
        }
        xbar();
        const float STAY2 = (2.0f - 3.0f) * L2E;
        int cur = 0;
        for (int t = 0; t < 256; t += 16) {
            {
                const int la = (t + 31 < 255) ? (t + 31) : 255;
                const int tbo = FWD ? (la >> 7) : ((511 - la) >> 7);
                if (tbo != have) { wait_tile(done, n * 4 + tbo); have = tbo; }
            }
            #pragma unroll
            for (int u = 0; u < 16; ++u) {
                const float g2 = val ? __builtin_amdgcn_logf(h2f(pv[u])) : NEGF;
                int tn = t + u + 16; if (tn > 255) tn = 255;
                const int row = FWD ? tn : (511 - tn);
                pv[u] = eb[(size_t)row * CG];
                float nb;
                if (FWD) nb = (q > 0)   ? abuf[cur * 256 + q - 1] : NEGF;
                else     nb = (q < 255) ? abuf[cur * 256 + q + 1] : NEGF;
                const float st = a + STAY2;
                const float mv = nb + g2;
                const float mx = fmaxf(st, mv);
                const float mn = fminf(st, mv);
                a = mx + __builtin_amdgcn_logf(1.f + __builtin_amdgcn_exp2f(mn - mx));
                abuf[(cur ^ 1) * 256 + q] = a;
                xbar();
                cur ^= 1;
            }
        }
        if (FWD) CAL[n * 256 + q] = a;
        else     CBE[n * 256 + q] = a;
    }
}

// ---------------- combine + loss: out[n] = -((un - logZ)/len) ----------------
__global__ __launch_bounds__(256) void combine2_kernel(
    const float* __restrict__ FA, const float* __restrict__ FAe,
    const float* __restrict__ FB, const float* __restrict__ FBe,
    const float* __restrict__ CAL, const float* __restrict__ CBE,
    const int* __restrict__ ys_lens,
    float* __restrict__ out)
{
    __shared__ float red[256];
    __shared__ float lz;
    const int n = blockIdx.x;
    const int q = threadIdx.x;
    float s = 0.f;
    #pragma unroll
    for (int k = 0; k < 4; ++k)
        s += FA[n * 1024 + 4 * q + k] * FB[n * 1024 + 4 * q + k];
    red[q] = s; __syncthreads();
    for (int off = 128; off > 0; off >>= 1) {
        if (q < off) red[q] += red[q + off];
        __syncthreads();
    }
    if (q == 0) lz = FAe[n] + FBe[n] + __builtin_amdgcn_logf(red[0]);
    __syncthreads();
    const float x = CAL[n * 256 + q] + CBE[n * 256 + q];
    red[q] = x; __syncthreads();
    for (int off = 128; off > 0; off >>= 1) {
        if (q < off) red[q] = fmaxf(red[q], red[q + off]);
        __syncthreads();
    }
    const float m = red[0]; __syncthreads();
    red[q] = __builtin_amdgcn_exp2f(x - m); __syncthreads();
    for (int off = 128; off > 0; off >>= 1) {
        if (q < off) red[q] += red[q + off];
        __syncthreads();
    }
    if (q == 0) {
        const float un = m + __builtin_amdgcn_logf(red[0]);
        out[n] = -(LN2 * (un - lz) / (float)ys_lens[n]);
    }
}

// ---------------- fallback GEMM (no workspace path) ----------------
__global__ __launch_bounds__(256) void crf_gemm_fallback(
    const unsigned short* __restrict__ A16,
    const unsigned short* __restrict__ W16,
    const float* __restrict__ bias,
    float* __restrict__ out)
{
    __shared__ unsigned short As[128 * 64];
    __shared__ unsigned short Bs[128 * 64];
    const int tid  = threadIdx.x;
    const int lane = tid & 63;
    const int wv   = __builtin_amdgcn_readfirstlane(tid >> 6);
    const int wr   = wv >> 1, wc = wv & 1;
    const int m0   = blockIdx.y * 128;
    const int n0   = blockIdx.x * 128;
    const int wbase = tid & 192;
    f32x4 acc[4][4];
    #pragma unroll
    for (int i = 0; i < 4; ++i)
        #pragma unroll
        for (int j = 0; j < 4; ++j) acc[i][j] = (f32x4){0.f, 0.f, 0.f, 0.f};
    const int l15 = lane & 15, lj = lane >> 4, l7 = lane & 7;
    for (int k0 = 0; k0 < D_IN; k0 += 64) {
        __syncthreads();
        #pragma unroll
        for (int i = 0; i < 4; ++i) {
            const int c   = i * 256 + tid;
            const int row = c >> 3;
            const int jg  = (c & 7) ^ (row & 7);
            const unsigned short* ga = A16 + (size_t)(m0 + row) * D_IN + k0 + jg * 8;
            const unsigned short* gb = W16 + (size_t)(n0 + row) * D_IN + k0 + jg * 8;
            gll16(ga, As + (size_t)(i * 256 + wbase) * 8);
            gll16(gb, Bs + (size_t)(i * 256 + wbase) * 8);
        }
        __syncthreads();
        #pragma unroll
        for (int ks = 0; ks < 2; ++ks) {
            bf16x8 af[4], bb[4];
            #pragma unroll
            for (int mi = 0; mi < 4; ++mi) {
                const int row = wr * 64 + mi * 16 + l15;
                const int jsw = (ks * 4 + lj) ^ l7;
                af[mi] = *reinterpret_cast<const bf16x8*>(&As[row * 64 + jsw * 8]);
            }
            #pragma unroll
            for (int ni = 0; ni < 4; ++ni) {
                const int row = wc * 64 + ni * 16 + l15;
                const int jsw = (ks * 4 + lj) ^ l7;
                bb[ni] = *reinterpret_cast<const bf16x8*>(&Bs[row * 64 + jsw * 8]);
            }
            #pragma unroll
            for (int mi = 0; mi < 4; ++mi)
                #pragma unroll
                for (int ni = 0; ni < 4; ++ni)
                    acc[mi][ni] = __builtin_amdgcn_mfma_f32_16x16x32_bf16(
                        af[mi], bb[ni], acc[mi][ni], 0, 0, 0);
        }
    }
    float bv[4];
    #pragma unroll
    for (int ni = 0; ni < 4; ++ni) bv[ni] = bias[n0 + wc * 64 + ni * 16 + l15];
    #pragma unroll
    for (int mi = 0; mi < 4; ++mi) {
        #pragma unroll
        for (int r = 0; r < 4; ++r) {
            const int m = m0 + wr * 64 + mi * 16 + lj * 4 + r;
            float* r1 = out + 16 + (size_t)m * CO;
            #pragma unroll
            for (int ni = 0; ni < 4; ++ni) {
                const int n = n0 + wc * 64 + ni * 16 + l15;
                const float v = tanh5(acc[mi][ni][r] + bv[ni]);
                const int ch = (n >> 2) * 5 + (n & 3) + 1;
                r1[ch] = v;
                r1[ch + SCORES_SZ] = v;
                if ((l15 & 3) == 0) {
                    r1[ch - 1] = 2.0f;
                    r1[ch - 1 + SCORES_SZ] = 2.0f;
                }
            }
        }
    }
}

// ---------------- fallback fused fwd on f32 interleaved scores (round-2, known-good) ----------------
__global__ __launch_bounds__(1024) void crf_fwd_kernel(
    const float* __restrict__ scores,
    const int* __restrict__ ys_pad,
    const int* __restrict__ ys_lens,
    float* __restrict__ ws)
{
    const int blk = blockIdx.x;
    const float STAY = 2.0f * L2E;
    if (blk < NB) {
        const int n = blk;
        const int s = threadIdx.x;
        __shared__ float buf[2][1024];
        __shared__ float red[1024];
        float alpha = 0.f;
        buf[0][s] = 0.f;
        const int j0 = s >> 2;
        const float* rowp = scores + (size_t)(n * T_STEPS) * CO + 5 * s + 1;
        float pm[4][4];
        #pragma unroll
        for (int u = 0; u < 4; ++u) {
            const float* r = rowp + (size_t)u * CO;
            pm[u][0] = r[0]; pm[u][1] = r[1]; pm[u][2] = r[2]; pm[u][3] = r[3];
        }
        __syncthreads();
        int cur = 0;
        for (int t = 0; t < T_STEPS; t += 4) {
            #pragma unroll
            for (int u = 0; u < 4; ++u) {
                const float m1 = pm[u][0], m2 = pm[u][1], m3 = pm[u][2], m4 = pm[u][3];
                int tp = t + u + 4; if (tp > T_STEPS - 1) tp = T_STEPS - 1;
                const float* r = rowp + (size_t)tp * CO;
                pm[u][0] = r[0]; pm[u][1] = r[1]; pm[u][2] = r[2]; pm[u][3] = r[3];
                const float b1 = buf[cur][j0];
                const float b2 = buf[cur][j0 + 256];
                const float b3 = buf[cur][j0 + 512];
                const float b4 = buf[cur][j0 + 768];
                const float a0 = alpha + STAY;
                const float a1 = fmaf(m1, L2E, b1);
                const float a2 = fmaf(m2, L2E, b2);
                const float a3 = fmaf(m3, L2E, b3);
                const float a4 = fmaf(m4, L2E, b4);
                const float mx = fmaxf(fmaxf(fmaxf(a0, a1), fmaxf(a2, a3)), a4);
                const float sum = __builtin_amdgcn_exp2f(a0 - mx) + __builtin_amdgcn_exp2f(a1 - mx)
                                + __builtin_amdgcn_exp2f(a2 - mx) + __builtin_amdgcn_exp2f(a3 - mx)
                                + __builtin_amdgcn_exp2f(a4 - mx);
                alpha = mx + __builtin_amdgcn_logf(sum);
                buf[cur ^ 1][s] = alpha;
                __syncthreads();
                cur ^= 1;
            }
        }
        red[s] = alpha;
        __syncthreads();
        for (int off = 512; off > 0; off >>= 1) {
            if (s < off) red[s] = fmaxf(red[s], red[s + off]);
            __syncthreads();
        }
        const float gmax = red[0];
        __syncthreads();
        red[s] = __builtin_amdgcn_exp2f(alpha - gmax);
        __syncthreads();
        for (int off = 512; off > 0; off >>= 1) {
            if (s < off) red[s] += red[s + off];
            __syncthreads();
        }
        if (s == 0) ws[n] = LN2 * (gmax + __builtin_amdgcn_logf(red[0]));
    } else {
        const int n = blk - NB;
        const int i = threadIdx.x;
        __shared__ float abuf[2][LMAX];
        __shared__ int tcl[256];
        if (i < 256) tcl[i] = max(ys_pad[n * 256 + i] - 1, 0);
        __syncthreads();
        int mch = -1;
        if (i >= 1 && i < LMAX) {
            const int code = tcl[i] * 256 + tcl[i + 1] * 64 + tcl[i + 2] * 16
                           + tcl[i + 3] * 4 + tcl[i + 4];
            mch = code * 5 + tcl[i - 1] + 1;
        }
        float alpha = (i == 0) ? 0.f : NEGF;
        if (i < LMAX) abuf[0][i] = alpha;
        const float* base = scores + (size_t)(n * T_STEPS) * CO;
        const size_t moff = (mch >= 0) ? (size_t)mch : 0;
        float pg[4];
        #pragma unroll
        for (int u = 0; u < 4; ++u) pg[u] = base[(size_t)u * CO + moff];
        __syncthreads();
        int cur = 0;
        for (int t = 0; t < T_STEPS; t += 4) {
            #pragma unroll
            for (int u = 0; u < 4; ++u) {
                const float g = pg[u];
                int tp = t + u + 4; if (tp > T_STEPS - 1) tp = T_STEPS - 1;
                pg[u] = base[(size_t)tp * CO + moff];
                if (i < LMAX) {
                    const float a_stay = alpha + STAY;
                    const float prev = (i > 0) ? abuf[cur][i - 1] : NEGF;
                    const float a_mv = (i > 0) ? fmaf(g, L2E, prev) : NEGF;
                    const float mx = fmaxf(a_stay, a_mv);
                    const float mn = fminf(a_stay, a_mv);
                    alpha = mx + __builtin_amdgcn_logf(1.f + __builtin_amdgcn_exp2f(mn - mx));
                    abuf[cur ^ 1][i] = alpha;
                }
                __syncthreads();
                cur ^= 1;
            }
        }
        if (i == ys_lens[n] - 5) ws[NB + n] = alpha * LN2;
    }
}

// ---------------- fallback loss ----------------
__global__ void crf_loss_kernel(const float* __restrict__ ws,
                                const int* __restrict__ ys_lens,
                                float* __restrict__ out)
{
    const int n = threadIdx.x;
    if (n < NB) {
        const float logz = ws[NB + n] - ws[n];
        out[n] = -(logz / (float)ys_lens[n]);
    }
}

extern "C" void kernel_launch(void* const* d_in, const int* in_sizes, int n_in,
                              void* d_out, int out_size, void* d_ws, size_t ws_size,
                              hipStream_t stream)
{
    const float* hs      = (const float*)d_in[0];
    const int*   ys_pad  = (const int*)d_in[2];
    const int*   ys_lens = (const int*)d_in[3];
    const float* W       = (const float*)d_in[4];
    const float* bias    = (const float*)d_in[5];
    float* out = (float*)d_out;
    float* ws  = (float*)d_ws;

    const size_t A_ELEMS = (size_t)8192 * 512;
    const size_t W_ELEMS = (size_t)4096 * 512;
    const size_t E_ELEMS = (size_t)8192 * 4096;
    const size_t X_FLOATS = (size_t)16 * 1024 * 2 + 32 + (size_t)16 * 256 * 2;
    const size_t NEED = 256 + (A_ELEMS + W_ELEMS + E_ELEMS) * 2 + X_FLOATS * 4;

    unsigned int* done = (unsigned int*)d_ws;                 // 64 counters in first 256B
    unsigned short* A16 = (unsigned short*)((char*)d_ws + 256);
    unsigned short* W16 = A16 + A_ELEMS;
    unsigned short* E16 = W16 + W_ELEMS;
    float* FA  = (float*)(E16 + E_ELEMS);
    float* FAe = FA + 16 * 1024;
    float* FB  = FAe + 16;
    float* FBe = FB + 16 * 1024;
    float* CAL = FBe + 16;
    float* CBE = CAL + 16 * 256;

    cvt_bf16_kernel<<<(int)(A_ELEMS / 4 / 256), 256, 0, stream>>>(hs, A16, (int)(A_ELEMS / 4));
    cvt_bf16_kernel<<<(int)(W_ELEMS / 4 / 256), 256, 0, stream>>>(W, W16, (int)(W_ELEMS / 4));

    if (ws_size >= NEED) {
        hipMemsetAsync(d_ws, 0, 256, stream);                 // reset tile flags every call
        mega_kernel<<<64 + 2048, 256, 0, stream>>>(A16, W16, bias, out, E16,
                                                   ys_pad, ys_lens, done,
                                                   FA, FAe, FB, FBe, CAL, CBE);
        combine2_kernel<<<16, 256, 0, stream>>>(FA, FAe, FB, FBe, CAL, CBE, ys_lens, out);
    } else {
        dim3 grid(CG / 128, (NB * T_STEPS) / 128);
        crf_gemm_fallback<<<grid, 256, 0, stream>>>(A16, W16, bias, out);
        crf_fwd_kernel<<<2 * NB, 1024, 0, stream>>>(out + 16, ys_pad, ys_lens, ws);
        crf_loss_kernel<<<1, 64, 0, stream>>>(ws, ys_lens, out);
    }
}

// Round 14
// 273.850 us; speedup vs baseline: 1.5909x; 1.5909x over previous
//
#include <hip/hip_runtime.h>
#include <hip/hip_bf16.h>
#include <hip/hip_fp16.h>
#include <math.h>

#define T_STEPS 512
#define NB      16
#define D_IN    512
#define CG      4096
#define CO      5120
#define LMAX    252
#define NEGF    (-1e30f)
#define SCORES_SZ 41943040LL   // NB * T_STEPS * CO
#define L2E 1.4426950408889634f
#define LN2 0.6931471805599453f
#define STAYT 0.36787944117144233f   // exp(2 - 3) tilted stay factor

typedef __attribute__((ext_vector_type(8))) short bf16x8;
typedef __attribute__((ext_vector_type(4))) float f32x4;

__device__ __forceinline__ float tanh5(float x) {
    x = fminf(fmaxf(x, -15.f), 15.f);
    float e = __expf(2.f * x);
    return 5.f * (e - 1.f) / (e + 1.f);
}
__device__ __forceinline__ unsigned short f2bf(float v) {
    __hip_bfloat16 h = __float2bfloat16(v);
    return *reinterpret_cast<unsigned short*>(&h);
}
__device__ __forceinline__ float h2f(unsigned short s) {
    union { unsigned short u; _Float16 h; } c; c.u = s;
    return (float)c.h;
}
__device__ __forceinline__ unsigned short f2h(float v) {
    union { unsigned short u; _Float16 h; } c; c.h = (_Float16)v;
    return c.u;
}
__device__ __forceinline__ void cvt8(uint4 u, float* g) {
    g[0] = h2f((unsigned short)(u.x & 0xffff)); g[1] = h2f((unsigned short)(u.x >> 16));
    g[2] = h2f((unsigned short)(u.y & 0xffff)); g[3] = h2f((unsigned short)(u.y >> 16));
    g[4] = h2f((unsigned short)(u.z & 0xffff)); g[5] = h2f((unsigned short)(u.z >> 16));
    g[6] = h2f((unsigned short)(u.w & 0xffff)); g[7] = h2f((unsigned short)(u.w >> 16));
}
__device__ __forceinline__ void gll16(const unsigned short* g, unsigned short* l) {
    __builtin_amdgcn_global_load_lds((const __attribute__((address_space(1))) void*)g,
                                     (__attribute__((address_space(3))) void*)l, 16, 0, 0);
}
// Skewed alpha index: state j lives at float offset j + (j>>5).
// Makes the float4 exchange reads/writes 2-way (free) instead of 8-way conflicted.
__device__ __forceinline__ int sk(int j) { return j + (j >> 5); }
// log2-domain logaddexp
__device__ __forceinline__ float laddexp2(float x, float y) {
    const float mx = fmaxf(x, y), mn = fminf(x, y);
    return mx + __builtin_amdgcn_logf(1.f + __builtin_amdgcn_exp2f(mn - mx));
}

// ---------------- fp32 -> bf16 conversion (RNE) ----------------
__global__ __launch_bounds__(256) void cvt_bf16_kernel(const float* __restrict__ src,
                                                       unsigned short* __restrict__ dst,
                                                       int n4) {
    int i = blockIdx.x * 256 + threadIdx.x;
    if (i < n4) {
        float4 v = *(reinterpret_cast<const float4*>(src) + i);
        ushort4 o;
        o.x = f2bf(v.x); o.y = f2bf(v.y); o.z = f2bf(v.z); o.w = f2bf(v.w);
        *(reinterpret_cast<ushort4*>(dst) + i) = o;
    }
}

// ---------------- bf16 MFMA GEMM + tanh*5 + blank interleave (+ tilted exp f16 copy) ----------------
template <bool WSE>
__global__ __launch_bounds__(256) void crf_gemm_bf16(
    const unsigned short* __restrict__ A16,
    const unsigned short* __restrict__ W16,
    const float* __restrict__ bias,
    float* __restrict__ out,
    unsigned short* __restrict__ e16)
{
    __shared__ unsigned short As[128 * 64];
    __shared__ unsigned short Bs[128 * 64];
    const int tid  = threadIdx.x;
    const int lane = tid & 63;
    const int wv   = __builtin_amdgcn_readfirstlane(tid >> 6);
    const int wr   = wv >> 1, wc = wv & 1;
    const int m0   = blockIdx.y * 128;
    const int n0   = blockIdx.x * 128;
    const int wbase = tid & 192;

    f32x4 acc[4][4];
    #pragma unroll
    for (int i = 0; i < 4; ++i)
        #pragma unroll
        for (int j = 0; j < 4; ++j) acc[i][j] = (f32x4){0.f, 0.f, 0.f, 0.f};

    const int l15 = lane & 15, lj = lane >> 4, l7 = lane & 7;

    for (int k0 = 0; k0 < D_IN; k0 += 64) {
        __syncthreads();
        #pragma unroll
        for (int i = 0; i < 4; ++i) {
            const int c   = i * 256 + tid;
            const int row = c >> 3;
            const int jg  = (c & 7) ^ (row & 7);
            const unsigned short* ga = A16 + (size_t)(m0 + row) * D_IN + k0 + jg * 8;
            const unsigned short* gb = W16 + (size_t)(n0 + row) * D_IN + k0 + jg * 8;
            gll16(ga, As + (size_t)(i * 256 + wbase) * 8);
            gll16(gb, Bs + (size_t)(i * 256 + wbase) * 8);
        }
        __syncthreads();
        #pragma unroll
        for (int ks = 0; ks < 2; ++ks) {
            bf16x8 af[4], bb[4];
            #pragma unroll
            for (int mi = 0; mi < 4; ++mi) {
                const int row = wr * 64 + mi * 16 + l15;
                const int jsw = (ks * 4 + lj) ^ l7;
                af[mi] = *reinterpret_cast<const bf16x8*>(&As[row * 64 + jsw * 8]);
            }
            #pragma unroll
            for (int ni = 0; ni < 4; ++ni) {
                const int row = wc * 64 + ni * 16 + l15;
                const int jsw = (ks * 4 + lj) ^ l7;
                bb[ni] = *reinterpret_cast<const bf16x8*>(&Bs[row * 64 + jsw * 8]);
            }
            #pragma unroll
            for (int mi = 0; mi < 4; ++mi)
                #pragma unroll
                for (int ni = 0; ni < 4; ++ni)
                    acc[mi][ni] = __builtin_amdgcn_mfma_f32_16x16x32_bf16(
                        af[mi], bb[ni], acc[mi][ni], 0, 0, 0);
        }
    }

    float bv[4];
    #pragma unroll
    for (int ni = 0; ni < 4; ++ni) bv[ni] = bias[n0 + wc * 64 + ni * 16 + l15];

    #pragma unroll
    for (int mi = 0; mi < 4; ++mi) {
        #pragma unroll
        for (int r = 0; r < 4; ++r) {
            const int m = m0 + wr * 64 + mi * 16 + lj * 4 + r;
            float* r1 = out + 16 + (size_t)m * CO;
            #pragma unroll
            for (int ni = 0; ni < 4; ++ni) {
                const int n = n0 + wc * 64 + ni * 16 + l15;
                const float v = tanh5(acc[mi][ni][r] + bv[ni]);
                const int ch = (n >> 2) * 5 + (n & 3) + 1;
                r1[ch] = v;
                r1[ch + SCORES_SZ] = v;
                if ((l15 & 3) == 0) {
                    r1[ch - 1] = 2.0f;
                    r1[ch - 1 + SCORES_SZ] = 2.0f;
                }
                if (WSE) e16[(size_t)m * CG + n] = f2h(__expf(v - 3.0f));
            }
        }
    }
}

// ---------------- fb6: 2-step-fused CRF (1 barrier / 2 steps) + barrier-free single-wave CTC ----------------
// 64 blocks x 256 threads. role: 0=CRF fwd, 1=CRF bwd, 2=CTC fwd, 3=CTC bwd.
// CRF: prob domain; per fused iter apply rows (r0,r1): compute intermediates for own states
// {4q+d} and shared {q+256m} from the 2-hop neighborhood; cross-term scores come from an
// LDS-staged copy of row r0 (each thread stages its own 32B chunk; the single per-iter
// barrier covers both alpha and stage). Skewed alpha layout sk(j) kills bank conflicts.
// CTC: 1 wave, 4 positions/lane, jacobi update (old neighbors) -> shfl only, NO barriers.
__global__ __launch_bounds__(256) void fb6_kernel(
    const unsigned short* __restrict__ e16,
    const int* __restrict__ ys_pad,
    const int* __restrict__ ys_lens,
    float* __restrict__ FA, float* __restrict__ FAe,
    float* __restrict__ FB, float* __restrict__ FBe,
    float* __restrict__ CAL, float* __restrict__ CBE)
{
    __shared__ uint4 SH4[1681];          // 26896 B
    const int role = blockIdx.x >> 4;
    const int n = blockIdx.x & 15;
    const int q = threadIdx.x;
    const int w = q >> 6, lane = q & 63;
    const unsigned short* eb = e16 + (size_t)(n * T_STEPS) * CG;

    if (role < 2) {
        uint4* st0 = SH4;                 // staged row, buf 0 (576 uint4)
        uint4* st1 = SH4 + 576;           // staged row, buf 1
        float* ab0 = (float*)(SH4 + 1152);       // skewed alpha (1056 f)
        float* ab1 = ab0 + 1056;
        float* wmax4 = (float*)(SH4 + 1680);
        const bool FWD = (role == 0);
        const unsigned short* ebq = eb + 16 * q;
        const int stIdx = 2 * q + (q >> 3);      // this thread's stage slot

        float P0 = 1.f, P1 = 1.f, P2 = 1.f, P3 = 1.f, acc = 0.f;
        *(float4*)&ab0[4 * q + (q >> 3)] = make_float4(1.f, 1.f, 1.f, 1.f);

        // ring: slot j holds (row0(j), row1(j)) own chunks for iter j (mod 4)
        uint4 pfA[4][2], pfB[4][2];
        #pragma unroll
        for (int j = 0; j < 4; ++j) {
            const int r0 = FWD ? (2 * j)     : (511 - 2 * j);
            const int r1 = FWD ? (2 * j + 1) : (510 - 2 * j);
            pfA[j][0] = *(const uint4*)(ebq + (size_t)r0 * CG);
            pfA[j][1] = *(const uint4*)(ebq + (size_t)r0 * CG + 8);
            pfB[j][0] = *(const uint4*)(ebq + (size_t)r1 * CG);
            pfB[j][1] = *(const uint4*)(ebq + (size_t)r1 * CG + 8);
        }
        // stage iter-0's first row
        st0[stIdx] = pfA[0][0]; st0[stIdx + 1] = pfA[0][1];
        __syncthreads();

        int cur = 0;
        const int h = __builtin_amdgcn_readfirstlane(q >> 6);   // wave-uniform (bwd)
        for (int t4 = 0; t4 < 128; t4 += 4) {
            #pragma unroll
            for (int u = 0; u < 4; ++u) {
                const int i = t4 + u;
                const uint4 oAa = pfA[u][0], oAb = pfA[u][1];   // first row own chunk
                const uint4 oBa = pfB[u][0], oBb = pfB[u][1];   // second row own chunk
                // prefetch iter i+4's rows into slot u
                {
                    int rn0, rn1;
                    if (FWD) { rn0 = 2 * (i + 4); if (rn0 > 255) rn0 = 255; rn1 = rn0 < 255 ? rn0 + 1 : 255; }
                    else     { rn0 = 511 - 2 * (i + 4); if (rn0 < 256) rn0 = 256; rn1 = rn0 > 256 ? rn0 - 1 : 256; }
                    pfA[u][0] = *(const uint4*)(ebq + (size_t)rn0 * CG);
                    pfA[u][1] = *(const uint4*)(ebq + (size_t)rn0 * CG + 8);
                    pfB[u][0] = *(const uint4*)(ebq + (size_t)rn1 * CG);
                    pfB[u][1] = *(const uint4*)(ebq + (size_t)rn1 * CG + 8);
                }
                float gA[16], gB[16];
                cvt8(oAa, gA); cvt8(oAb, gA + 8);
                cvt8(oBa, gB); cvt8(oBb, gB + 8);
                const float* abR = (cur == 0) ? ab0 : ab1;
                float* abW = (cur == 0) ? ab1 : ab0;
                const uint4* stR = ((i & 1) == 0) ? st0 : st1;
                uint4* stW = ((i & 1) == 0) ? st1 : st0;
                float o0, o1, o2, o3;
                if (FWD) {
                    // A_m = P[q+256m]
                    const float A0a = abR[sk(q)];
                    const float A1a = abR[sk(q + 256)];
                    const float A2a = abR[sk(q + 512)];
                    const float A3a = abR[sk(q + 768)];
                    // I[4q+d] (own intermediates)
                    float I0 = fmaf(STAYT, P0, fmaf(gA[0],  A0a, gA[1]  * A1a) + fmaf(gA[2],  A2a, gA[3]  * A3a));
                    float I1 = fmaf(STAYT, P1, fmaf(gA[4],  A0a, gA[5]  * A1a) + fmaf(gA[6],  A2a, gA[7]  * A3a));
                    float I2 = fmaf(STAYT, P2, fmaf(gA[8],  A0a, gA[9]  * A1a) + fmaf(gA[10], A2a, gA[11] * A3a));
                    float I3 = fmaf(STAYT, P3, fmaf(gA[12], A0a, gA[13] * A1a) + fmaf(gA[14], A2a, gA[15] * A3a));
                    // I[q+256m]: sources C[m][k] = P[(q>>2)+64m+256k]; scores from staged row
                    float Im[4];
                    const int jb = q >> 2;
                    const int o  = (4 * q) & 15;
                    const int hi8 = o >> 3;
                    const bool sel = (o & 4) != 0;
                    #pragma unroll
                    for (int m = 0; m < 4; ++m) {
                        const int qc = jb + 64 * m;
                        const uint4 sv = stR[2 * qc + (qc >> 3) + hi8];
                        const unsigned int w0 = sel ? sv.z : sv.x;
                        const unsigned int w1 = sel ? sv.w : sv.y;
                        const float c0 = abR[sk(jb + 64 * m)];
                        const float c1 = abR[sk(jb + 64 * m + 256)];
                        const float c2 = abR[sk(jb + 64 * m + 512)];
                        const float c3 = abR[sk(jb + 64 * m + 768)];
                        const float Amv = (m == 0) ? A0a : (m == 1) ? A1a : (m == 2) ? A2a : A3a;
                        Im[m] = fmaf(STAYT, Amv,
                                 fmaf(h2f((unsigned short)(w0 & 0xffff)), c0,
                                      h2f((unsigned short)(w0 >> 16)) * c1)
                               + fmaf(h2f((unsigned short)(w1 & 0xffff)), c2,
                                      h2f((unsigned short)(w1 >> 16)) * c3));
                    }
                    o0 = fmaf(STAYT, I0, fmaf(gB[0],  Im[0], gB[1]  * Im[1]) + fmaf(gB[2],  Im[2], gB[3]  * Im[3]));
                    o1 = fmaf(STAYT, I1, fmaf(gB[4],  Im[0], gB[5]  * Im[1]) + fmaf(gB[6],  Im[2], gB[7]  * Im[3]));
                    o2 = fmaf(STAYT, I2, fmaf(gB[8],  Im[0], gB[9]  * Im[1]) + fmaf(gB[10], Im[2], gB[11] * Im[3]));
                    o3 = fmaf(STAYT, I3, fmaf(gB[12], Im[0], gB[13] * Im[1]) + fmaf(gB[14], Im[2], gB[15] * Im[3]));
                } else {
                    // D_d = B[4q+d]
                    const float4 D = *(const float4*)&abR[4 * q + (q >> 3)];
                    // J[q+256m] own intermediates
                    float Jm0 = fmaf(STAYT, P0, fmaf(gA[0], D.x, gA[4] * D.y) + fmaf(gA[8],  D.z, gA[12] * D.w));
                    float Jm1 = fmaf(STAYT, P1, fmaf(gA[1], D.x, gA[5] * D.y) + fmaf(gA[9],  D.z, gA[13] * D.w));
                    float Jm2 = fmaf(STAYT, P2, fmaf(gA[2], D.x, gA[6] * D.y) + fmaf(gA[10], D.z, gA[14] * D.w));
                    float Jm3 = fmaf(STAYT, P3, fmaf(gA[3], D.x, gA[7] * D.y) + fmaf(gA[11], D.z, gA[15] * D.w));
                    // J[4q+d]: sources B[4r+d2], r=(4q+d)&255; scores chunk r of staged row, offsets {h,4+h,8+h,12+h}
                    float Jd[4];
                    const float Dd[4] = {D.x, D.y, D.z, D.w};
                    #pragma unroll
                    for (int d = 0; d < 4; ++d) {
                        const int r = (4 * q + d) & 255;
                        const float4 S = *(const float4*)&abR[4 * r + (r >> 3)];
                        const int idx = 2 * r + (r >> 3);
                        const uint4 sa = stR[idx];
                        const uint4 sb = stR[idx + 1];
                        const unsigned int wa0 = (h & 2) ? sa.y : sa.x;
                        const unsigned int wa1 = (h & 2) ? sa.w : sa.z;
                        const unsigned int wb0 = (h & 2) ? sb.y : sb.x;
                        const unsigned int wb1 = (h & 2) ? sb.w : sb.z;
                        const float e0 = h2f((unsigned short)((h & 1) ? (wa0 >> 16) : (wa0 & 0xffff)));
                        const float e1 = h2f((unsigned short)((h & 1) ? (wa1 >> 16) : (wa1 & 0xffff)));
                        const float e2 = h2f((unsigned short)((h & 1) ? (wb0 >> 16) : (wb0 & 0xffff)));
                        const float e3 = h2f((unsigned short)((h & 1) ? (wb1 >> 16) : (wb1 & 0xffff)));
                        Jd[d] = fmaf(STAYT, Dd[d], fmaf(e0, S.x, e1 * S.y) + fmaf(e2, S.z, e3 * S.w));
                    }
                    o0 = fmaf(STAYT, Jm0, fmaf(gB[0], Jd[0], gB[4] * Jd[1]) + fmaf(gB[8],  Jd[2], gB[12] * Jd[3]));
                    o1 = fmaf(STAYT, Jm1, fmaf(gB[1], Jd[0], gB[5] * Jd[1]) + fmaf(gB[9],  Jd[2], gB[13] * Jd[3]));
                    o2 = fmaf(STAYT, Jm2, fmaf(gB[2], Jd[0], gB[6] * Jd[1]) + fmaf(gB[10], Jd[2], gB[14] * Jd[3]));
                    o3 = fmaf(STAYT, Jm3, fmaf(gB[3], Jd[0], gB[7] * Jd[1]) + fmaf(gB[11], Jd[2], gB[15] * Jd[3]));
                }
                if ((i & 3) == 1) {
                    const float wm = fmaxf(fmaxf(wmax4[0], wmax4[1]), fmaxf(wmax4[2], wmax4[3]));
                    const int e = (int)((__float_as_uint(wm) >> 23) & 0xff) - 127;
                    const float c = __uint_as_float((unsigned)(127 - e) << 23);
                    o0 *= c; o1 *= c; o2 *= c; o3 *= c;
                    acc += (float)e;
                }
                P0 = o0; P1 = o1; P2 = o2; P3 = o3;
                if (FWD) {
                    *(float4*)&abW[4 * q + (q >> 3)] = make_float4(P0, P1, P2, P3);
                } else {
                    abW[sk(q)]       = P0;
                    abW[sk(q + 256)] = P1;
                    abW[sk(q + 512)] = P2;
                    abW[sk(q + 768)] = P3;
                }
                if ((i & 3) == 0) {
                    float m = fmaxf(fmaxf(P0, P1), fmaxf(P2, P3));
                    #pragma unroll
                    for (int msk = 1; msk < 64; msk <<= 1)
                        m = fmaxf(m, __shfl_xor(m, msk, 64));
                    if (lane == 0) wmax4[w] = m;
                }
                if (i < 127) {
                    const uint4 s0 = pfA[(u + 1) & 3][0];
                    const uint4 s1 = pfA[(u + 1) & 3][1];
                    stW[stIdx] = s0; stW[stIdx + 1] = s1;
                }
                __syncthreads();
                cur ^= 1;
            }
        }
        if (FWD) {
            FA[n * 1024 + 4 * q + 0] = P0;
            FA[n * 1024 + 4 * q + 1] = P1;
            FA[n * 1024 + 4 * q + 2] = P2;
            FA[n * 1024 + 4 * q + 3] = P3;
            if (q == 0) FAe[n] = acc;
        } else {
            FB[n * 1024 + q]       = P0;
            FB[n * 1024 + q + 256] = P1;
            FB[n * 1024 + q + 512] = P2;
            FB[n * 1024 + q + 768] = P3;
            if (q == 0) FBe[n] = acc;
        }
    } else {
        // ---------------- CTC: single wave, jacobi, barrier-free ----------------
        int* tcl = (int*)SH4;
        tcl[q] = max(ys_pad[n * 256 + q] - 1, 0);
        __syncthreads();
        if (q >= 64) return;
        const bool FWD = (role == 2);
        const int L = q;
        int mch[4]; bool val[4];
        #pragma unroll
        for (int d = 0; d < 4; ++d) {
            const int p = 4 * L + d;
            if (FWD) {
                val[d] = (p >= 1 && p < LMAX);
                if (val[d]) {
                    const int code = tcl[p] * 256 + tcl[p + 1] * 64 + tcl[p + 2] * 16
                                   + tcl[p + 3] * 4 + tcl[p + 4];
                    mch[d] = code * 4 + tcl[p - 1];
                } else mch[d] = 0;
            } else {
                val[d] = (p < LMAX - 1);
                if (val[d]) {
                    const int code = tcl[p + 1] * 256 + tcl[p + 2] * 64 + tcl[p + 3] * 16
                                   + tcl[p + 4] * 4 + tcl[p + 5];
                    mch[d] = code * 4 + tcl[p];
                } else mch[d] = 0;
            }
        }
        const int li = ys_lens[n] - 5;
        float a0, a1, a2, a3;
        if (FWD) {
            a0 = (4 * L == 0) ? 0.f : NEGF; a1 = NEGF; a2 = NEGF; a3 = NEGF;
        } else {
            a0 = (4 * L + 0 == li) ? 0.f : NEGF;
            a1 = (4 * L + 1 == li) ? 0.f : NEGF;
            a2 = (4 * L + 2 == li) ? 0.f : NEGF;
            a3 = (4 * L + 3 == li) ? 0.f : NEGF;
        }
        unsigned short pv[8][4];
        #pragma unroll
        for (int s = 0; s < 8; ++s) {
            const int row = FWD ? s : (511 - s);
            #pragma unroll
            for (int d = 0; d < 4; ++d) pv[s][d] = eb[(size_t)row * CG + mch[d]];
        }
        const float ST2 = (2.0f - 3.0f) * L2E;
        for (int t = 0; t < 256; t += 8) {
            #pragma unroll
            for (int u = 0; u < 8; ++u) {
                float g0 = val[0] ? __builtin_amdgcn_logf(h2f(pv[u][0])) : NEGF;
                float g1 = val[1] ? __builtin_amdgcn_logf(h2f(pv[u][1])) : NEGF;
                float g2 = val[2] ? __builtin_amdgcn_logf(h2f(pv[u][2])) : NEGF;
                float g3 = val[3] ? __builtin_amdgcn_logf(h2f(pv[u][3])) : NEGF;
                int tn = t + u + 8; if (tn > 255) tn = 255;
                const int row = FWD ? tn : (511 - tn);
                #pragma unroll
                for (int d = 0; d < 4; ++d) pv[u][d] = eb[(size_t)row * CG + mch[d]];
                float n0, n1, n2, n3;
                if (FWD) {
                    float pA = __shfl_up(a3, 1, 64);
                    if (L == 0) pA = NEGF;
                    n0 = laddexp2(a0 + ST2, pA + g0);
                    n1 = laddexp2(a1 + ST2, a0 + g1);
                    n2 = laddexp2(a2 + ST2, a1 + g2);
                    n3 = laddexp2(a3 + ST2, a2 + g3);
                } else {
                    float nP = __shfl_down(a0, 1, 64);
                    if (L == 63) nP = NEGF;
                    n3 = laddexp2(a3 + ST2, nP + g3);
                    n2 = laddexp2(a2 + ST2, a3 + g2);
                    n1 = laddexp2(a1 + ST2, a2 + g1);
                    n0 = laddexp2(a0 + ST2, a1 + g0);
                }
                a0 = n0; a1 = n1; a2 = n2; a3 = n3;
            }
        }
        float* dst = FWD ? CAL : CBE;
        dst[n * 256 + 4 * L + 0] = a0;
        dst[n * 256 + 4 * L + 1] = a1;
        dst[n * 256 + 4 * L + 2] = a2;
        dst[n * 256 + 4 * L + 3] = a3;
    }
}

// ---------------- combine + loss: out[n] = -((un - logZ)/len) ----------------
__global__ __launch_bounds__(256) void combine2_kernel(
    const float* __restrict__ FA, const float* __restrict__ FAe,
    const float* __restrict__ FB, const float* __restrict__ FBe,
    const float* __restrict__ CAL, const float* __restrict__ CBE,
    const int* __restrict__ ys_lens,
    float* __restrict__ out)
{
    __shared__ float red[256];
    __shared__ float lz;
    const int n = blockIdx.x;
    const int q = threadIdx.x;
    float s = 0.f;
    #pragma unroll
    for (int k = 0; k < 4; ++k)
        s += FA[n * 1024 + 4 * q + k] * FB[n * 1024 + 4 * q + k];
    red[q] = s; __syncthreads();
    for (int off = 128; off > 0; off >>= 1) {
        if (q < off) red[q] += red[q + off];
        __syncthreads();
    }
    if (q == 0) lz = FAe[n] + FBe[n] + __builtin_amdgcn_logf(red[0]);
    __syncthreads();
    const float x = CAL[n * 256 + q] + CBE[n * 256 + q];
    red[q] = x; __syncthreads();
    for (int off = 128; off > 0; off >>= 1) {
        if (q < off) red[q] = fmaxf(red[q], red[q + off]);
        __syncthreads();
    }
    const float m = red[0]; __syncthreads();
    red[q] = __builtin_amdgcn_exp2f(x - m); __syncthreads();
    for (int off = 128; off > 0; off >>= 1) {
        if (q < off) red[q] += red[q + off];
        __syncthreads();
    }
    if (q == 0) {
        const float un = m + __builtin_amdgcn_logf(red[0]);
        out[n] = -(LN2 * (un - lz) / (float)ys_lens[n]);
    }
}

// ---------------- fallback fused fwd on f32 interleaved scores (round-2, known-good) ----------------
__global__ __launch_bounds__(1024) void crf_fwd_kernel(
    const float* __restrict__ scores,
    const int* __restrict__ ys_pad,
    const int* __restrict__ ys_lens,
    float* __restrict__ ws)
{
    const int blk = blockIdx.x;
    const float STAY = 2.0f * L2E;
    if (blk < NB) {
        const int n = blk;
        const int s = threadIdx.x;
        __shared__ float buf[2][1024];
        __shared__ float red[1024];
        float alpha = 0.f;
        buf[0][s] = 0.f;
        const int j0 = s >> 2;
        const float* rowp = scores + (size_t)(n * T_STEPS) * CO + 5 * s + 1;
        float pm[4][4];
        #pragma unroll
        for (int u = 0; u < 4; ++u) {
            const float* r = rowp + (size_t)u * CO;
            pm[u][0] = r[0]; pm[u][1] = r[1]; pm[u][2] = r[2]; pm[u][3] = r[3];
        }
        __syncthreads();
        int cur = 0;
        for (int t = 0; t < T_STEPS; t += 4) {
            #pragma unroll
            for (int u = 0; u < 4; ++u) {
                const float m1 = pm[u][0], m2 = pm[u][1], m3 = pm[u][2], m4 = pm[u][3];
                int tp = t + u + 4; if (tp > T_STEPS - 1) tp = T_STEPS - 1;
                const float* r = rowp + (size_t)tp * CO;
                pm[u][0] = r[0]; pm[u][1] = r[1]; pm[u][2] = r[2]; pm[u][3] = r[3];
                const float b1 = buf[cur][j0];
                const float b2 = buf[cur][j0 + 256];
                const float b3 = buf[cur][j0 + 512];
                const float b4 = buf[cur][j0 + 768];
                const float a0 = alpha + STAY;
                const float a1 = fmaf(m1, L2E, b1);
                const float a2 = fmaf(m2, L2E, b2);
                const float a3 = fmaf(m3, L2E, b3);
                const float a4 = fmaf(m4, L2E, b4);
                const float mx = fmaxf(fmaxf(fmaxf(a0, a1), fmaxf(a2, a3)), a4);
                const float sum = __builtin_amdgcn_exp2f(a0 - mx) + __builtin_amdgcn_exp2f(a1 - mx)
                                + __builtin_amdgcn_exp2f(a2 - mx) + __builtin_amdgcn_exp2f(a3 - mx)
                                + __builtin_amdgcn_exp2f(a4 - mx);
                alpha = mx + __builtin_amdgcn_logf(sum);
                buf[cur ^ 1][s] = alpha;
                __syncthreads();
                cur ^= 1;
            }
        }
        red[s] = alpha;
        __syncthreads();
        for (int off = 512; off > 0; off >>= 1) {
            if (s < off) red[s] = fmaxf(red[s], red[s + off]);
            __syncthreads();
        }
        const float gmax = red[0];
        __syncthreads();
        red[s] = __builtin_amdgcn_exp2f(alpha - gmax);
        __syncthreads();
        for (int off = 512; off > 0; off >>= 1) {
            if (s < off) red[s] += red[s + off];
            __syncthreads();
        }
        if (s == 0) ws[n] = LN2 * (gmax + __builtin_amdgcn_logf(red[0]));
    } else {
        const int n = blk - NB;
        const int i = threadIdx.x;
        __shared__ float abuf[2][LMAX];
        __shared__ int tcl[256];
        if (i < 256) tcl[i] = max(ys_pad[n * 256 + i] - 1, 0);
        __syncthreads();
        int mch = -1;
        if (i >= 1 && i < LMAX) {
            const int code = tcl[i] * 256 + tcl[i + 1] * 64 + tcl[i + 2] * 16
                           + tcl[i + 3] * 4 + tcl[i + 4];
            mch = code * 5 + tcl[i - 1] + 1;
        }
        float alpha = (i == 0) ? 0.f : NEGF;
        if (i < LMAX) abuf[0][i] = alpha;
        const float* base = scores + (size_t)(n * T_STEPS) * CO;
        const size_t moff = (mch >= 0) ? (size_t)mch : 0;
        float pg[4];
        #pragma unroll
        for (int u = 0; u < 4; ++u) pg[u] = base[(size_t)u * CO + moff];
        __syncthreads();
        int cur = 0;
        for (int t = 0; t < T_STEPS; t += 4) {
            #pragma unroll
            for (int u = 0; u < 4; ++u) {
                const float g = pg[u];
                int tp = t + u + 4; if (tp > T_STEPS - 1) tp = T_STEPS - 1;
                pg[u] = base[(size_t)tp * CO + moff];
                if (i < LMAX) {
                    const float a_stay = alpha + STAY;
                    const float prev = (i > 0) ? abuf[cur][i - 1] : NEGF;
                    const float a_mv = (i > 0) ? fmaf(g, L2E, prev) : NEGF;
                    const float mx = fmaxf(a_stay, a_mv);
                    const float mn = fminf(a_stay, a_mv);
                    alpha = mx + __builtin_amdgcn_logf(1.f + __builtin_amdgcn_exp2f(mn - mx));
                    abuf[cur ^ 1][i] = alpha;
                }
                __syncthreads();
                cur ^= 1;
            }
        }
        if (i == ys_lens[n] - 5) ws[NB + n] = alpha * LN2;
    }
}

// ---------------- fallback loss ----------------
__global__ void crf_loss_kernel(const float* __restrict__ ws,
                                const int* __restrict__ ys_lens,
                                float* __restrict__ out)
{
    const int n = threadIdx.x;
    if (n < NB) {
        const float logz = ws[NB + n] - ws[n];
        out[n] = -(logz / (float)ys_lens[n]);
    }
}

extern "C" void kernel_launch(void* const* d_in, const int* in_sizes, int n_in,
                              void* d_out, int out_size, void* d_ws, size_t ws_size,
                              hipStream_t stream)
{
    const float* hs      = (const float*)d_in[0];
    const int*   ys_pad  = (const int*)d_in[2];
    const int*   ys_lens = (const int*)d_in[3];
    const float* W       = (const float*)d_in[4];
    const float* bias    = (const float*)d_in[5];
    float* out = (float*)d_out;
    float* ws  = (float*)d_ws;

    const size_t A_ELEMS = (size_t)8192 * 512;
    const size_t W_ELEMS = (size_t)4096 * 512;
    const size_t E_ELEMS = (size_t)8192 * 4096;
    const size_t X_FLOATS = (size_t)16 * 1024 * 2 + 32 + (size_t)16 * 256 * 2;
    const size_t NEED = 256 + (A_ELEMS + W_ELEMS + E_ELEMS) * 2 + X_FLOATS * 4;

    unsigned short* A16 = (unsigned short*)((char*)d_ws + 256);
    unsigned short* W16 = A16 + A_ELEMS;
    unsigned short* E16 = W16 + W_ELEMS;
    float* FA  = (float*)(E16 + E_ELEMS);
    float* FAe = FA + 16 * 1024;
    float* FB  = FAe + 16;
    float* FBe = FB + 16 * 1024;
    float* CAL = FBe + 16;
    float* CBE = CAL + 16 * 256;

    cvt_bf16_kernel<<<(int)(A_ELEMS / 4 / 256), 256, 0, stream>>>(hs, A16, (int)(A_ELEMS / 4));
    cvt_bf16_kernel<<<(int)(W_ELEMS / 4 / 256), 256, 0, stream>>>(W, W16, (int)(W_ELEMS / 4));
    dim3 grid(CG / 128, (NB * T_STEPS) / 128);

    if (ws_size >= NEED) {
        crf_gemm_bf16<true><<<grid, 256, 0, stream>>>(A16, W16, bias, out, E16);
        fb6_kernel<<<64, 256, 0, stream>>>(E16, ys_pad, ys_lens, FA, FAe, FB, FBe, CAL, CBE);
        combine2_kernel<<<16, 256, 0, stream>>>(FA, FAe, FB, FBe, CAL, CBE, ys_lens, out);
    } else {
        crf_gemm_bf16<false><<<grid, 256, 0, stream>>>(A16, W16, bias, out, nullptr);
        crf_fwd_kernel<<<2 * NB, 1024, 0, stream>>>(out + 16, ys_pad, ys_lens, ws);
        crf_loss_kernel<<<1, 64, 0, stream>>>(ws, ys_lens, out);
    }
}